// Round 7
// baseline (110525.183 us; speedup 1.0000x reference)
//
#include <hip/hip_runtime.h>

#define H 50
#define T 65536
#define NTHREADS 832

// ws layout (floats)
#define WC1_OFF 0        // 200 x 64 row-major (rows permuted j*4+gate)
#define BC1_OFF 12800    // 200
#define BC2_OFF 13000    // 200
#define WS2_OFF 13200    // 800 roles x 32 (cell-2 per-thread register slices)

// Wc1 cols: 0..6 = W_ih1[:,0:7], 7 = W_ih1[:,7] (err), 8..57 = W_hh1, 58..63 = 0
// ws2 role rho = unit*16 + pair*8 + slice: 2 gate-rows {2*pair, 2*pair+1} x
//   cols [13*slice, 13*slice+13) of [W_ih2 | W_hh2] (cols >= 100 -> 0).
//   Row A at rho*32+[0..12], row B at rho*32+[16..28].
__global__ void prep_kernel(const float* __restrict__ Wih1, const float* __restrict__ Whh1,
                            const float* __restrict__ bih1, const float* __restrict__ bhh1,
                            const float* __restrict__ Wih2, const float* __restrict__ Whh2,
                            const float* __restrict__ bih2, const float* __restrict__ bhh2,
                            float* __restrict__ ws) {
  int idx = blockIdx.x * blockDim.x + threadIdx.x;
  if (idx < 12800) {
    int r = idx >> 6, c = idx & 63;
    int j = r >> 2, gate = r & 3, orig = gate * 50 + j;
    float v = 0.f;
    if (c < 8) v = Wih1[orig * 8 + c];
    else if (c < 58) v = Whh1[orig * 50 + (c - 8)];
    ws[WC1_OFF + idx] = v;
  }
  if (idx < 200) {
    int j = idx >> 2, gate = idx & 3, orig = gate * 50 + j;
    ws[BC1_OFF + idx] = bih1[orig] + bhh1[orig];
    ws[BC2_OFF + idx] = bih2[orig] + bhh2[orig];
  }
  if (idx < 25600) {
    int rho = idx >> 5, j = idx & 31;
    int u = rho >> 4, sub = rho & 15, pr = sub >> 3, s = sub & 7;
    int rw = j >> 4, jj = j & 15;
    int col = 13 * s + jj;
    float v = 0.f;
    if (jj < 13 && col < 100) {
      int orig = (2 * pr + rw) * 50 + u;
      v = (col < 50) ? Wih2[orig * 50 + col] : Whh2[orig * 50 + (col - 50)];
    }
    ws[WS2_OFF + idx] = v;
  }
}

__device__ __forceinline__ float sigm(float x) {
  return __builtin_amdgcn_rcpf(1.f + __expf(-x));
}
__device__ __forceinline__ float tanh_(float x) {
  return 1.f - 2.f * __builtin_amdgcn_rcpf(1.f + __expf(2.f * x));
}
// LDS-only barrier: no vmcnt drain (out-stores / x-prefetch float across it).
__device__ __forceinline__ void bar() {
  asm volatile("s_waitcnt lgkmcnt(0)\n\ts_barrier" ::: "memory");
}
template<int CTRL>
__device__ __forceinline__ float dpp_add(float x) {
  int y = __builtin_amdgcn_mov_dpp(__float_as_int(x), CTRL, 0xF, 0xF, true);
  return x + __int_as_float(y);
}
// partner value at lane^8 within the 16-lane row (row_ror:8)
__device__ __forceinline__ float dpp_xor8(float x) {
  return __int_as_float(__builtin_amdgcn_mov_dpp(__float_as_int(x), 0x128, 0xF, 0xF, true));
}
__device__ __forceinline__ float dot4(float4 w, float4 u) {
  return w.x * u.x + w.y * u.y + w.z * u.z + w.w * u.w;
}
#define PINF(x) asm volatile("" : "+v"(x))
__device__ __forceinline__ void pin4(float4& v) { PINF(v.x); PINF(v.y); PINF(v.z); PINF(v.w); }

// Thread map (832 = 13 waves):
//   tids 0..799   : cell-2 (unit=tid>>4, pair=bit3, slice=tid&7), 26 weight regs
//   tids 400..799 : ALSO cell-1 (unit=(tid-400)>>3, slice=(tid-400)&7), Wc1 from LDS
//   tids 800..807 : x loaders ; tids 0..63 : phase-Y reduce
// Peak live ~60 VGPR -> below every allocation observed in R1-R6 (56..88):
// nothing left for the occupancy-chasing allocator to spill.
__global__ void __launch_bounds__(NTHREADS)
__attribute__((amdgpu_waves_per_eu(4, 4)))
lstm_kernel(const float* __restrict__ xseq,
            const float* __restrict__ ws,
            const float* __restrict__ Wout,
            const float* __restrict__ bout,
            float* __restrict__ out) {
  // Wc1 in LDS, segment-rotated: source (row r, col c) ->
  //   LW1[r*64 + 4*((2*(c>>3) + ((c>>2)&1) + ((r>>2)&1)) & 15) + (c&3)]
  // so each quarter-wave's 16 b128 reads cover all 8 bank-positions 2x (free).
  __shared__ float LW1[12800];
  // U1: dense [0..6]=x_t [7]=err [8..57]=h1 [58..63]=0  (phase-A input)
  // U2: 8 slices x stride 20; slice s holds cols [13s,13s+13) of [h1(50)|h2(50)]
  __shared__ __align__(16) float U1[2][64];
  __shared__ __align__(16) float U2[2][160];
  __shared__ float ACT[2];

  const int tid = threadIdx.x;

  for (int i = tid; i < 12800; i += NTHREADS) {
    int r = i >> 6, c = i & 63;
    int seg = (2 * (c >> 3) + ((c >> 2) & 1) + ((r >> 2) & 1)) & 15;
    LW1[r * 64 + 4 * seg + (c & 3)] = ws[WC1_OFF + i];
  }
  for (int i = tid; i < 128; i += NTHREADS) ((float*)U1)[i] = 0.f;
  for (int i = tid; i < 320; i += NTHREADS) ((float*)U2)[i] = 0.f;
  if (tid < 2) ACT[tid] = 0.f;

  const bool isC2 = (tid < 800);
  const bool isC1 = (tid >= 400 && tid < 800);
  const bool isLd = (tid >= 800 && tid < 808);

  // cell-2 role decode
  const int un2 = tid >> 4, sub = tid & 15, s2 = sub & 7;
  // cell-1 role decode
  const int q1 = tid - 400;
  const int un1 = q1 >> 3, s1 = q1 & 7;

  // ---- cell-2 weights: 26 floats + 2 biases per thread (registers) ----
  float4 wA0 = {0,0,0,0}, wA1 = {0,0,0,0}, wA2 = {0,0,0,0};
  float4 wB0 = {0,0,0,0}, wB1 = {0,0,0,0}, wB2 = {0,0,0,0};
  float wA3 = 0.f, wB3 = 0.f, bbA = 0.f, bbB = 0.f;
  if (isC2) {
    const float* wp = ws + WS2_OFF + (tid << 5);
    wA0 = *(const float4*)(wp);      wA1 = *(const float4*)(wp + 4);
    wA2 = *(const float4*)(wp + 8);  wA3 = wp[12];
    wB0 = *(const float4*)(wp + 16); wB1 = *(const float4*)(wp + 20);
    wB2 = *(const float4*)(wp + 24); wB3 = wp[28];
    bbA = ws[BC2_OFF + 4 * un2 + 2 * (sub >> 3) + 0];
    bbB = ws[BC2_OFF + 4 * un2 + 2 * (sub >> 3) + 1];
  }
  pin4(wA0); pin4(wA1); pin4(wA2); pin4(wB0); pin4(wB1); pin4(wB2);
  PINF(wA3); PINF(wB3); PINF(bbA); PINF(bbB);

  // ---- cell-1 loop-invariants: LDS bases + biases ----
  float4 b1 = {0, 0, 0, 0};
  int wb0 = 0, d1 = 4, h1posA = 0, h1posB = 0;
  if (isC1) {
    int rot = un1 & 1;
    wb0 = 256 * un1 + 8 * s1 + 4 * rot;            // k=0, first 16B chunk
    d1 = (2 * s1 + rot == 15) ? -60 : 4;           // second-chunk delta (seg wrap)
    b1 = *(const float4*)(ws + BC1_OFF + 4 * un1);
    h1posA = (un1 / 13) * 20 + un1 % 13;           // h1 -> U2 slot
    h1posB = 8 + un1;                              // h1 -> U1next slot
  }
  pin4(b1);

  float c1 = 0.f, c2 = 0.f, err = 0.f, xr = 0.f;
  float wo = (tid < 50) ? Wout[tid] : 0.f;
  float bo = bout[0];
  PINF(wo); PINF(bo);
  const int ycol = 50 + ((tid & 63) < 50 ? (tid & 63) : 0);
  const int yoff = (ycol / 13) * 20 + ycol % 13;
  const int h2pos = ((50 + un2) / 13) * 20 + (50 + un2) % 13;

  if (isLd) {               // depth-2 x prefetch pipeline
    int c = tid - 800;
    float v0 = xseq[c];
    if (c < 7) U1[0][c] = v0; else ACT[0] = v0;
    xr = xseq[8 + c];
  }
  __syncthreads();

  for (int t = 0; t < T; ++t) {
    const int par = t & 1;

    // ---------- Phase A: cell-1 (threads 400..799, Wc1 from LDS) ----------
    if (isC1) {
      float4 x0 = *(const float4*)&U1[par][8 * s1];
      float4 x1 = *(const float4*)&U1[par][8 * s1 + 4];
      float a0, a1, a2, a3;
      { float4 wa = *(const float4*)&LW1[wb0];
        float4 wb = *(const float4*)&LW1[wb0 + d1];
        a0 = dot4(wa, x0) + dot4(wb, x1); }
      { float4 wa = *(const float4*)&LW1[wb0 + 64];
        float4 wb = *(const float4*)&LW1[wb0 + 64 + d1];
        a1 = dot4(wa, x0) + dot4(wb, x1); }
      { float4 wa = *(const float4*)&LW1[wb0 + 128];
        float4 wb = *(const float4*)&LW1[wb0 + 128 + d1];
        a2 = dot4(wa, x0) + dot4(wb, x1); }
      { float4 wa = *(const float4*)&LW1[wb0 + 192];
        float4 wb = *(const float4*)&LW1[wb0 + 192 + d1];
        a3 = dot4(wa, x0) + dot4(wb, x1); }
      a0 = dpp_add<0xB1>(a0); a0 = dpp_add<0x4E>(a0); a0 = dpp_add<0x141>(a0);
      a1 = dpp_add<0xB1>(a1); a1 = dpp_add<0x4E>(a1); a1 = dpp_add<0x141>(a1);
      a2 = dpp_add<0xB1>(a2); a2 = dpp_add<0x4E>(a2); a2 = dpp_add<0x141>(a2);
      a3 = dpp_add<0xB1>(a3); a3 = dpp_add<0x4E>(a3); a3 = dpp_add<0x141>(a3);
      if (s1 == 0) {   // owns unit un1: rows 4u+{0,1,2,3} = i,f,g,o
        float gi = sigm (a0 + b1.x);
        float gf = sigm (a1 + b1.y);
        float gg = tanh_(a2 + b1.z);
        float go = sigm (a3 + b1.w);
        c1 = gf * c1 + gi * gg;
        float h1 = go * tanh_(c1);
        U2[par][h1posA]     = h1;   // for cell-2 this step
        U1[par ^ 1][h1posB] = h1;   // for cell-1 next step
      }
    }
    bar();
    // ---------- Phase C: cell-2 (threads 0..799, register weights) -------
    if (isC2) {
      const float* ub = &U2[par][20 * s2];
      float4 y0 = *(const float4*)(ub);
      float4 y1 = *(const float4*)(ub + 4);
      float4 y2 = *(const float4*)(ub + 8);
      float y3 = ub[12];
      float aA = dot4(wA0, y0) + dot4(wA1, y1) + dot4(wA2, y2) + wA3 * y3;
      float aB = dot4(wB0, y0) + dot4(wB1, y1) + dot4(wB2, y2) + wB3 * y3;
      aA = dpp_add<0xB1>(aA); aA = dpp_add<0x4E>(aA); aA = dpp_add<0x141>(aA);
      aB = dpp_add<0xB1>(aB); aB = dpp_add<0x4E>(aB); aB = dpp_add<0x141>(aB);
      aA += bbA; aB += bbB;
      float pA = dpp_xor8(aA);   // partner pair's sums ({g,o} seen from {i,f})
      float pB = dpp_xor8(aB);
      if (sub == 0) {            // pair==0, slice==0: owns unit un2
        float gi = sigm (aA);
        float gf = sigm (aB);
        float gg = tanh_(pA);
        float go = sigm (pB);
        c2 = gf * c2 + gi * gg;
        float h2 = go * tanh_(c2);
        U2[par ^ 1][h2pos] = h2;  // for y(t) and cell-2 next step
      }
    } else if (isLd) {
      int c = tid - 800;
      if (c < 7) U1[par ^ 1][c] = xr; else ACT[par ^ 1] = xr;  // publish x(t+1)
      int nt = (t + 2 < T) ? t + 2 : T - 1;
      xr = xseq[nt * 8 + c];                                   // fetch x(t+2)
    }
    bar();
    // ---------- Phase Y: y, out store, err update (wave 0) ---------------
    if (tid < 64) {
      float v = U2[par ^ 1][yoff] * wo;   // wo=0 for lanes >=50
      v = dpp_add<0xB1>(v); v = dpp_add<0x4E>(v);
      v = dpp_add<0x141>(v); v = dpp_add<0x140>(v);
      v = v + __int_as_float(__builtin_amdgcn_ds_swizzle(__float_as_int(v), 0x401F));
      float vlo = __int_as_float(__builtin_amdgcn_readlane(__float_as_int(v), 0));
      float vhi = __int_as_float(__builtin_amdgcn_readlane(__float_as_int(v), 32));
      if (tid == 0) {
        float y = vlo + vhi + bo;
        out[t] = y;                       // fire-and-forget
        err = 0.9f * err + 0.1f * (ACT[par] - y);
        U1[par ^ 1][7] = err;
      }
    }
    bar();
  }
}

extern "C" void kernel_launch(void* const* d_in, const int* in_sizes, int n_in,
                              void* d_out, int out_size, void* d_ws, size_t ws_size,
                              hipStream_t stream) {
  const float* xseq = (const float*)d_in[0];
  const float* Wih1 = (const float*)d_in[1];
  const float* Whh1 = (const float*)d_in[2];
  const float* bih1 = (const float*)d_in[3];
  const float* bhh1 = (const float*)d_in[4];
  const float* Wih2 = (const float*)d_in[5];
  const float* Whh2 = (const float*)d_in[6];
  const float* bih2 = (const float*)d_in[7];
  const float* bhh2 = (const float*)d_in[8];
  const float* Wout = (const float*)d_in[9];
  const float* bout = (const float*)d_in[10];
  float* ws = (float*)d_ws;

  prep_kernel<<<100, 256, 0, stream>>>(Wih1, Whh1, bih1, bhh1,
                                       Wih2, Whh2, bih2, bhh2, ws);
  lstm_kernel<<<1, NTHREADS, 0, stream>>>(xseq, ws, Wout, bout, (float*)d_out);
}